// Round 1
// 125.455 us; speedup vs baseline: 1.0176x; 1.0176x over previous
//
#include <hip/hip_runtime.h>
#include <hip/hip_fp16.h>
#include <math.h>

#define NREL    3
#define EDGES   200000
#define DIM     128
#define PASSES  5
#define UNITS   6250          // EDGES / 32
#define BJ      313           // ceil(UNITS / (4*PASSES))
#define JPER    (6 * BJ)      // (ro, bj) pairs per XCD slot

#define NDRUG   8000
#define NDIS    18000
#define DRUG_ELEMS (NDRUG * DIM)             // 1,024,000
#define TOT_ELEMS  ((NDRUG + NDIS) * DIM)    // 3,328,000

typedef _Float16 half8 __attribute__((ext_vector_type(8)));

// Pre-pass: fp32 tables -> fp16 (concatenated [drug | disease]) in d_ws.
__global__ __launch_bounds__(256) void convert_fp16(
    const float* __restrict__ drug, const float* __restrict__ dis,
    _Float16* __restrict__ o)
{
    const int i = blockIdx.x * 256 + threadIdx.x;   // half8 index
    const int nd8 = DRUG_ELEMS / 8, nt8 = TOT_ELEMS / 8;
    if (i >= nt8) return;
    const float4* s; int j;
    if (i < nd8) { s = (const float4*)drug; j = i * 2; }
    else         { s = (const float4*)dis;  j = (i - nd8) * 2; }
    const float4 x = s[j], y = s[j + 1];
    half8 h;
    h[0] = (_Float16)x.x; h[1] = (_Float16)x.y;
    h[2] = (_Float16)x.z; h[3] = (_Float16)x.w;
    h[4] = (_Float16)y.x; h[5] = (_Float16)y.y;
    h[6] = (_Float16)y.z; h[7] = (_Float16)y.w;
    ((half8*)o)[i] = h;
}

// Gather: 2 chunks of 64 dims (128 B fp16), chunk pinned to an XCD quad via
// blockIdx%8 (XCD pinning verified R2: FETCH 418->32 MB).
// R(this): the VGPR=32 compile of the previous version proves the staged
// 10-load pipeline was collapsed by the register-pressure scheduler (needs
// 40+ VGPRs of live loads). Force it: launch_bounds(256,6) raises the VGPR
// cap to ~85, and sched_barrier(0) pins all row gathers before compute.
// Dot product uses (float)a*(float)b -> v_fma_mix_f32 (f32 math from f16
// operands, same rounding as before, ~half the VALU ops).
__global__ __launch_bounds__(256, 6) void distmult_fp16(
    const _Float16* __restrict__ tabs,   // [drug fp16 | disease fp16]
    const float* __restrict__ W,
    const int* __restrict__ drug_src, const int* __restrict__ dis_dst,
    const int* __restrict__ dis_src,  const int* __restrict__ drug_dst,
    float* __restrict__ part0,           // = d_out, chunk-0 partials
    float* __restrict__ part1)           // = ws,    chunk-1 partials
{
    const int b     = blockIdx.x;
    const int slot  = b & 7;        // XCD slot
    const int chunk = slot >> 2;    // 0..1 -> dims [64*chunk, +64)
    const int q     = slot & 3;     // 4 XCDs per chunk share the edge units
    const int j     = b >> 3;
    const int ro    = j / BJ;       // 0..5 (0..2 fwd, 3..5 rev)
    const int bj    = j % BJ;

    const int eg   = threadIdx.x >> 3;  // 0..31 edge within pass
    const int lane = threadIdx.x & 7;   // 0..7: 8 halfs (16 B) per lane

    const _Float16* tabD = tabs;
    const _Float16* tabS = tabs + DRUG_ELEMS;
    const _Float16 *tabA, *tabB; const int *idxA, *idxB;
    if (ro < NREL) {
        tabA = tabD; tabB = tabS;
        idxA = drug_src + ro * EDGES;
        idxB = dis_dst  + ro * EDGES;
    } else {
        tabA = tabS; tabB = tabD;
        idxA = dis_src  + (ro - NREL) * EDGES;
        idxB = drug_dst + (ro - NREL) * EDGES;
    }

    const int off = chunk * 64 + lane * 8;            // element offset in row
    const float4 wlo = *(const float4*)(W + ro * DIM + off);
    const float4 whi = *(const float4*)(W + ro * DIM + off + 4);
    // Pre-offset base pointers: row address becomes saddr + (idx<<8).
    const _Float16* tA = tabA + off;
    const _Float16* tB = tabB + off;
    float* pbase = (chunk == 0 ? part0 : part1) + (size_t)ro * EDGES;

    // Stage 1: all index loads in flight. u/valid/uc are block-uniform
    // (q, bj uniform; p constexpr) -> SGPR, e[p] = uc*32 + eg.
    int e[PASSES], ia[PASSES], ib[PASSES];
    bool valid[PASSES];
    #pragma unroll
    for (int p = 0; p < PASSES; ++p) {
        const int u = q + 4 * (p + PASSES * bj);
        valid[p] = (u < UNITS);
        const int uc = valid[p] ? u : (UNITS - 1);
        e[p]  = uc * 32 + eg;
        ia[p] = __builtin_nontemporal_load(idxA + e[p]);
        ib[p] = __builtin_nontemporal_load(idxB + e[p]);
    }

    // Stage 2: ALL 10 row gathers issued before any compute.
    half8 a8[PASSES], b8[PASSES];
    #pragma unroll
    for (int p = 0; p < PASSES; ++p) {
        a8[p] = *(const half8*)(tA + ia[p] * DIM);
        b8[p] = *(const half8*)(tB + ib[p] * DIM);
    }
    // Pin: forbid the scheduler from sinking gathers into stage 3
    // (this is what silently happened at VGPR_Count=32).
    __builtin_amdgcn_sched_barrier(0);

    // Stage 3: triple-dot via mix-precision FMA, 8-lane reduce, store.
    #pragma unroll
    for (int p = 0; p < PASSES; ++p) {
        float s = 0.0f;
        s = fmaf((float)a8[p][0] * (float)b8[p][0], wlo.x, s);
        s = fmaf((float)a8[p][1] * (float)b8[p][1], wlo.y, s);
        s = fmaf((float)a8[p][2] * (float)b8[p][2], wlo.z, s);
        s = fmaf((float)a8[p][3] * (float)b8[p][3], wlo.w, s);
        s = fmaf((float)a8[p][4] * (float)b8[p][4], whi.x, s);
        s = fmaf((float)a8[p][5] * (float)b8[p][5], whi.y, s);
        s = fmaf((float)a8[p][6] * (float)b8[p][6], whi.z, s);
        s = fmaf((float)a8[p][7] * (float)b8[p][7], whi.w, s);
        s += __shfl_xor(s, 4, 64);
        s += __shfl_xor(s, 2, 64);
        s += __shfl_xor(s, 1, 64);
        if (lane == 0 && valid[p])
            __builtin_nontemporal_store(s, pbase + e[p]);
    }
}

// Pass 3: out = sigmoid(out + part1), streaming.
__global__ __launch_bounds__(256) void reduce_sigmoid(
    const float* __restrict__ part1, float* __restrict__ out)
{
    const int i = blockIdx.x * 256 + threadIdx.x;     // float4 index
    if (i >= (6 * EDGES) / 4) return;
    float4 v = ((const float4*)out)[i];
    const float4 a = ((const float4*)part1)[i];
    v.x = 1.0f / (1.0f + __expf(-(v.x + a.x)));
    v.y = 1.0f / (1.0f + __expf(-(v.y + a.y)));
    v.z = 1.0f / (1.0f + __expf(-(v.z + a.z)));
    v.w = 1.0f / (1.0f + __expf(-(v.w + a.w)));
    ((float4*)out)[i] = v;
}

// ---- fallback (fp32 atomic path) if ws is too small ----
__global__ __launch_bounds__(256) void distmult_atomic(
    const float* __restrict__ h_drug, const float* __restrict__ h_disease,
    const float* __restrict__ W,
    const int* __restrict__ drug_src, const int* __restrict__ dis_dst,
    const int* __restrict__ dis_src, const int* __restrict__ drug_dst,
    float* __restrict__ out)
{
    const int b = blockIdx.x;
    const int slot = b & 7, chunk = slot >> 1, half = slot & 1;
    const int j = b >> 3;
    const int ro = j / 625, batch = j % 625;
    const int eg = threadIdx.x >> 3, lane = threadIdx.x & 7;

    const float* tabA; const float* tabB;
    const int* idxA; const int* idxB;
    if (ro < NREL) {
        tabA = h_drug;    tabB = h_disease;
        idxA = drug_src + (size_t)ro * EDGES;
        idxB = dis_dst  + (size_t)ro * EDGES;
    } else {
        tabA = h_disease; tabB = h_drug;
        idxA = dis_src  + (size_t)(ro - NREL) * EDGES;
        idxB = drug_dst + (size_t)(ro - NREL) * EDGES;
    }
    const int off = chunk * 32;
    const float4 w4 = ((const float4*)(W + (size_t)ro * DIM + off))[lane];

    #pragma unroll
    for (int p = 0; p < 5; ++p) {
        const int e = batch * 320 + p * 64 + half * 32 + eg;
        const int ia = __builtin_nontemporal_load(idxA + e);
        const int ib = __builtin_nontemporal_load(idxB + e);
        const float4 a4 = ((const float4*)(tabA + (size_t)ia * DIM + off))[lane];
        const float4 b4 = ((const float4*)(tabB + (size_t)ib * DIM + off))[lane];
        float s = a4.x * w4.x * b4.x + a4.y * w4.y * b4.y
                + a4.z * w4.z * b4.z + a4.w * w4.w * b4.w;
        s += __shfl_xor(s, 4, 64);
        s += __shfl_xor(s, 2, 64);
        s += __shfl_xor(s, 1, 64);
        if (lane == 0) atomicAdd(&out[(size_t)ro * EDGES + e], s);
    }
}

__global__ __launch_bounds__(256) void sigmoid_inplace(float* __restrict__ out)
{
    const int i = blockIdx.x * 256 + threadIdx.x;
    if (i >= (6 * EDGES) / 4) return;
    float4 v = ((float4*)out)[i];
    v.x = 1.0f / (1.0f + __expf(-v.x));
    v.y = 1.0f / (1.0f + __expf(-v.y));
    v.z = 1.0f / (1.0f + __expf(-v.z));
    v.w = 1.0f / (1.0f + __expf(-v.w));
    ((float4*)out)[i] = v;
}

extern "C" void kernel_launch(void* const* d_in, const int* in_sizes, int n_in,
                              void* d_out, int out_size, void* d_ws, size_t ws_size,
                              hipStream_t stream) {
    const float* h_drug    = (const float*)d_in[0];
    const float* h_disease = (const float*)d_in[1];
    const float* W         = (const float*)d_in[2];
    const int*   drug_src  = (const int*)d_in[3];
    const int*   dis_dst   = (const int*)d_in[4];
    const int*   dis_src   = (const int*)d_in[5];
    const int*   drug_dst  = (const int*)d_in[6];
    float*       out       = (float*)d_out;

    const int n4 = (6 * EDGES) / 4;                       // 300000
    const size_t tab_bytes = (size_t)TOT_ELEMS * 2;       // 6,656,000
    const size_t ws_need   = tab_bytes + (size_t)6 * EDGES * sizeof(float); // 11.46 MB

    if (ws_size >= ws_need) {
        _Float16* tabs  = (_Float16*)d_ws;
        float*    part1 = (float*)((char*)d_ws + tab_bytes);

        convert_fp16<<<(TOT_ELEMS / 8 + 255) / 256, 256, 0, stream>>>(
            h_drug, h_disease, tabs);
        distmult_fp16<<<8 * JPER, 256, 0, stream>>>(
            tabs, W, drug_src, dis_dst, dis_src, drug_dst, out, part1);
        reduce_sigmoid<<<(n4 + 255) / 256, 256, 0, stream>>>(part1, out);
    } else {
        hipMemsetAsync(out, 0, (size_t)6 * EDGES * sizeof(float), stream);
        distmult_atomic<<<8 * 6 * 625, 256, 0, stream>>>(
            h_drug, h_disease, W, drug_src, dis_dst, dis_src, drug_dst, out);
        sigmoid_inplace<<<(n4 + 255) / 256, 256, 0, stream>>>(out);
    }
}

// Round 3
// 115.455 us; speedup vs baseline: 1.1058x; 1.0866x over previous
//
#include <hip/hip_runtime.h>
#include <hip/hip_fp16.h>
#include <math.h>

#define NREL    3
#define EDGES   200000
#define DIM     128
#define PASSES  5
#define UNITS   6250          // EDGES / 32
#define BJ      313           // ceil(UNITS / (4*PASSES))
#define JPER    (6 * BJ)      // (ro, bj) pairs per XCD slot

#define NDRUG   8000
#define NDIS    18000
#define DRUG_ELEMS (NDRUG * DIM)             // 1,024,000
#define TOT_ELEMS  ((NDRUG + NDIS) * DIM)    // 3,328,000

typedef _Float16 half8 __attribute__((ext_vector_type(8)));

// Pre-pass: fp32 tables -> fp16 (concatenated [drug | disease]) in d_ws.
__global__ __launch_bounds__(256) void convert_fp16(
    const float* __restrict__ drug, const float* __restrict__ dis,
    _Float16* __restrict__ o)
{
    const int i = blockIdx.x * 256 + threadIdx.x;   // half8 index
    const int nd8 = DRUG_ELEMS / 8, nt8 = TOT_ELEMS / 8;
    if (i >= nt8) return;
    const float4* s; int j;
    if (i < nd8) { s = (const float4*)drug; j = i * 2; }
    else         { s = (const float4*)dis;  j = (i - nd8) * 2; }
    const float4 x = s[j], y = s[j + 1];
    half8 h;
    h[0] = (_Float16)x.x; h[1] = (_Float16)x.y;
    h[2] = (_Float16)x.z; h[3] = (_Float16)x.w;
    h[4] = (_Float16)y.x; h[5] = (_Float16)y.y;
    h[6] = (_Float16)y.z; h[7] = (_Float16)y.w;
    ((half8*)o)[i] = h;
}

// R2 history: XCD chunk pinning (FETCH 418->32MB). R5: VGPR=36 proved the
// compiler collapses any source-level staged pipeline (sched_barrier alone
// did not stop DAG-level sinking of plain loads). R6(this): ALL vmem as
// inline asm (mutually ordered, unsinkable) + hand-counted vmcnt waits.
// Queue: 10 idx loads, 2 W loads, vmcnt(2), 10 row gathers, then
// progressive vmcnt(8/6/4/2/0) per compute pass. Waits are BARE asm
// followed by sched_barrier(0) -- the rule-#18 verified fence (tied
// multi-reg operands don't compile: "tied indirect register inputs").
// Stores buffered to the end so they never enter the counted queue.
__global__ __launch_bounds__(256, 4) void distmult_fp16(
    const _Float16* __restrict__ tabs,   // [drug fp16 | disease fp16]
    const float* __restrict__ W,
    const int* __restrict__ drug_src, const int* __restrict__ dis_dst,
    const int* __restrict__ dis_src,  const int* __restrict__ drug_dst,
    float* __restrict__ part0,           // = d_out, chunk-0 partials
    float* __restrict__ part1)           // = ws,    chunk-1 partials
{
    const int b     = blockIdx.x;
    const int slot  = b & 7;        // XCD slot
    const int chunk = slot >> 2;    // 0..1 -> dims [64*chunk, +64)
    const int q     = slot & 3;     // 4 XCDs per chunk share the edge units
    const int j     = b >> 3;
    const int ro    = j / BJ;       // 0..5 (0..2 fwd, 3..5 rev)
    const int bj    = j % BJ;

    const int eg   = threadIdx.x >> 3;  // 0..31 edge within pass
    const int lane = threadIdx.x & 7;   // 0..7: 8 halfs (16 B) per lane

    const _Float16* tabD = tabs;
    const _Float16* tabS = tabs + DRUG_ELEMS;
    const _Float16 *tabA, *tabB; const int *idxA, *idxB;
    if (ro < NREL) {
        tabA = tabD; tabB = tabS;
        idxA = drug_src + ro * EDGES;
        idxB = dis_dst  + ro * EDGES;
    } else {
        tabA = tabS; tabB = tabD;
        idxA = dis_src  + (ro - NREL) * EDGES;
        idxB = drug_dst + (ro - NREL) * EDGES;
    }

    const int off = chunk * 64 + lane * 8;            // element offset in row
    const _Float16* tA = tabA + off;                  // pre-offset bases
    const _Float16* tB = tabB + off;
    float* pbase = (chunk == 0 ? part0 : part1) + (size_t)ro * EDGES;

    // ---- Stage 1: issue ALL 10 index loads (oldest in the vmcnt queue). ----
    int e[PASSES];
    bool valid[PASSES];
    int ia[PASSES], ib[PASSES];
    #pragma unroll
    for (int p = 0; p < PASSES; ++p) {
        const int u = q + 4 * (p + PASSES * bj);
        valid[p] = (u < UNITS);
        const int uc = valid[p] ? u : (UNITS - 1);
        e[p] = uc * 32 + eg;
        asm volatile("global_load_dword %0, %1, off"
                     : "=v"(ia[p]) : "v"(idxA + e[p]));
        asm volatile("global_load_dword %0, %1, off"
                     : "=v"(ib[p]) : "v"(idxB + e[p]));
    }

    // ---- Stage 2: W loads (2 newest; still in flight while idx complete). --
    float4 wlo, whi;
    asm volatile("global_load_dwordx4 %0, %1, off"
                 : "=v"(wlo) : "v"(W + ro * DIM + off));
    asm volatile("global_load_dwordx4 %0, %1, off"
                 : "=v"(whi) : "v"(W + ro * DIM + off + 4));

    // Wait: all 10 idx done (W's 2 loads may remain outstanding).
    asm volatile("s_waitcnt vmcnt(2)");
    __builtin_amdgcn_sched_barrier(0);

    // ---- Stage 3: ALL 10 row gathers in flight (12 outstanding w/ W). ----
    half8 a8[PASSES], b8[PASSES];
    #pragma unroll
    for (int p = 0; p < PASSES; ++p) {
        asm volatile("global_load_dwordx4 %0, %1, off"
                     : "=v"(a8[p]) : "v"(tA + ia[p] * DIM));
        asm volatile("global_load_dwordx4 %0, %1, off"
                     : "=v"(b8[p]) : "v"(tB + ib[p] * DIM));
    }

    // ---- Stage 4: per-pass compute behind progressive counted waits. ----
    // Queue (oldest->newest) at this point: W.lo, W.hi, a0,b0,a1,b1,...,a4,b4.
    float res[PASSES];

#define DOT(p)                                                              \
    {                                                                       \
        float s = 0.0f;                                                     \
        s = fmaf((float)a8[p][0] * (float)b8[p][0], wlo.x, s);              \
        s = fmaf((float)a8[p][1] * (float)b8[p][1], wlo.y, s);              \
        s = fmaf((float)a8[p][2] * (float)b8[p][2], wlo.z, s);              \
        s = fmaf((float)a8[p][3] * (float)b8[p][3], wlo.w, s);              \
        s = fmaf((float)a8[p][4] * (float)b8[p][4], whi.x, s);              \
        s = fmaf((float)a8[p][5] * (float)b8[p][5], whi.y, s);              \
        s = fmaf((float)a8[p][6] * (float)b8[p][6], whi.z, s);              \
        s = fmaf((float)a8[p][7] * (float)b8[p][7], whi.w, s);              \
        s += __shfl_xor(s, 4, 64);                                          \
        s += __shfl_xor(s, 2, 64);                                          \
        s += __shfl_xor(s, 1, 64);                                          \
        res[p] = s;                                                         \
    }

    asm volatile("s_waitcnt vmcnt(8)");     // W.lo, W.hi, a0, b0 landed
    __builtin_amdgcn_sched_barrier(0);
    DOT(0)
    asm volatile("s_waitcnt vmcnt(6)");     // a1, b1 landed
    __builtin_amdgcn_sched_barrier(0);
    DOT(1)
    asm volatile("s_waitcnt vmcnt(4)");
    __builtin_amdgcn_sched_barrier(0);
    DOT(2)
    asm volatile("s_waitcnt vmcnt(2)");
    __builtin_amdgcn_sched_barrier(0);
    DOT(3)
    asm volatile("s_waitcnt vmcnt(0)");
    __builtin_amdgcn_sched_barrier(0);
    DOT(4)
#undef DOT

    // ---- Stage 5: stores last, so they never enter the counted queue. ----
    if (lane == 0) {
        #pragma unroll
        for (int p = 0; p < PASSES; ++p)
            if (valid[p])
                __builtin_nontemporal_store(res[p], pbase + e[p]);
    }
}

// Pass 3: out = sigmoid(out + part1), streaming.
__global__ __launch_bounds__(256) void reduce_sigmoid(
    const float* __restrict__ part1, float* __restrict__ out)
{
    const int i = blockIdx.x * 256 + threadIdx.x;     // float4 index
    if (i >= (6 * EDGES) / 4) return;
    float4 v = ((const float4*)out)[i];
    const float4 a = ((const float4*)part1)[i];
    v.x = 1.0f / (1.0f + __expf(-(v.x + a.x)));
    v.y = 1.0f / (1.0f + __expf(-(v.y + a.y)));
    v.z = 1.0f / (1.0f + __expf(-(v.z + a.z)));
    v.w = 1.0f / (1.0f + __expf(-(v.w + a.w)));
    ((float4*)out)[i] = v;
}

// ---- fallback (fp32 atomic path) if ws is too small ----
__global__ __launch_bounds__(256) void distmult_atomic(
    const float* __restrict__ h_drug, const float* __restrict__ h_disease,
    const float* __restrict__ W,
    const int* __restrict__ drug_src, const int* __restrict__ dis_dst,
    const int* __restrict__ dis_src, const int* __restrict__ drug_dst,
    float* __restrict__ out)
{
    const int b = blockIdx.x;
    const int slot = b & 7, chunk = slot >> 1, half = slot & 1;
    const int j = b >> 3;
    const int ro = j / 625, batch = j % 625;
    const int eg = threadIdx.x >> 3, lane = threadIdx.x & 7;

    const float* tabA; const float* tabB;
    const int* idxA; const int* idxB;
    if (ro < NREL) {
        tabA = h_drug;    tabB = h_disease;
        idxA = drug_src + (size_t)ro * EDGES;
        idxB = dis_dst  + (size_t)ro * EDGES;
    } else {
        tabA = h_disease; tabB = h_drug;
        idxA = dis_src  + (size_t)(ro - NREL) * EDGES;
        idxB = drug_dst + (size_t)(ro - NREL) * EDGES;
    }
    const int off = chunk * 32;
    const float4 w4 = ((const float4*)(W + (size_t)ro * DIM + off))[lane];

    #pragma unroll
    for (int p = 0; p < 5; ++p) {
        const int e = batch * 320 + p * 64 + half * 32 + eg;
        const int ia = __builtin_nontemporal_load(idxA + e);
        const int ib = __builtin_nontemporal_load(idxB + e);
        const float4 a4 = ((const float4*)(tabA + (size_t)ia * DIM + off))[lane];
        const float4 b4 = ((const float4*)(tabB + (size_t)ib * DIM + off))[lane];
        float s = a4.x * w4.x * b4.x + a4.y * w4.y * b4.y
                + a4.z * w4.z * b4.z + a4.w * w4.w * b4.w;
        s += __shfl_xor(s, 4, 64);
        s += __shfl_xor(s, 2, 64);
        s += __shfl_xor(s, 1, 64);
        if (lane == 0) atomicAdd(&out[(size_t)ro * EDGES + e], s);
    }
}

__global__ __launch_bounds__(256) void sigmoid_inplace(float* __restrict__ out)
{
    const int i = blockIdx.x * 256 + threadIdx.x;
    if (i >= (6 * EDGES) / 4) return;
    float4 v = ((float4*)out)[i];
    v.x = 1.0f / (1.0f + __expf(-v.x));
    v.y = 1.0f / (1.0f + __expf(-v.y));
    v.z = 1.0f / (1.0f + __expf(-v.z));
    v.w = 1.0f / (1.0f + __expf(-v.w));
    ((float4*)out)[i] = v;
}

extern "C" void kernel_launch(void* const* d_in, const int* in_sizes, int n_in,
                              void* d_out, int out_size, void* d_ws, size_t ws_size,
                              hipStream_t stream) {
    const float* h_drug    = (const float*)d_in[0];
    const float* h_disease = (const float*)d_in[1];
    const float* W         = (const float*)d_in[2];
    const int*   drug_src  = (const int*)d_in[3];
    const int*   dis_dst   = (const int*)d_in[4];
    const int*   dis_src   = (const int*)d_in[5];
    const int*   drug_dst  = (const int*)d_in[6];
    float*       out       = (float*)d_out;

    const int n4 = (6 * EDGES) / 4;                       // 300000
    const size_t tab_bytes = (size_t)TOT_ELEMS * 2;       // 6,656,000
    const size_t ws_need   = tab_bytes + (size_t)6 * EDGES * sizeof(float); // 11.46 MB

    if (ws_size >= ws_need) {
        _Float16* tabs  = (_Float16*)d_ws;
        float*    part1 = (float*)((char*)d_ws + tab_bytes);

        convert_fp16<<<(TOT_ELEMS / 8 + 255) / 256, 256, 0, stream>>>(
            h_drug, h_disease, tabs);
        distmult_fp16<<<8 * JPER, 256, 0, stream>>>(
            tabs, W, drug_src, dis_dst, dis_src, drug_dst, out, part1);
        reduce_sigmoid<<<(n4 + 255) / 256, 256, 0, stream>>>(part1, out);
    } else {
        (void)hipMemsetAsync(out, 0, (size_t)6 * EDGES * sizeof(float), stream);
        distmult_atomic<<<8 * 6 * 625, 256, 0, stream>>>(
            h_drug, h_disease, W, drug_src, dis_dst, dis_src, drug_dst, out);
        sigmoid_inplace<<<(n4 + 255) / 256, 256, 0, stream>>>(out);
    }
}